// Round 4
// baseline (194.719 us; speedup 1.0000x reference)
//
#include <hip/hip_runtime.h>
#include <hip/hip_bf16.h>

#define BATCH 32
#define LSEQ  512
#define NDIM  1024
#define NSPLIT 16

typedef __attribute__((ext_vector_type(8))) short bf16x8;
typedef __attribute__((ext_vector_type(4))) float f32x4;

__device__ __forceinline__ unsigned short f2bf(float x) {
    __hip_bfloat16 h = __float2bfloat16(x);
    return __builtin_bit_cast(unsigned short, h);
}

// ---------------------------------------------------------------------------
// Kernel 1: fused X fp32 -> bf16 conversion + s1/s2 partial sums
// (reverted to the R1 float4 form; R3's float2 z-split was neutral)
// ---------------------------------------------------------------------------
__global__ __launch_bounds__(256) void prep_kernel(
    const float* __restrict__ X, const float* __restrict__ W,
    unsigned short* __restrict__ Xb, float* __restrict__ P1, float* __restrict__ P2)
{
    __shared__ float sw[2 * LSEQ];
    int tid = threadIdx.x;
    for (int i = tid; i < 2 * LSEQ; i += 256) sw[i] = W[i];
    __syncthreads();

    int b  = blockIdx.y;
    int sp = blockIdx.x;
    int l0 = sp * (LSEQ / NSPLIT);
    size_t base = ((size_t)b * LSEQ + l0) * NDIM + tid * 4;
    const float* xp = X + base;
    unsigned short* xbp = Xb + base;

    float a0=0,a1=0,a2=0,a3=0, c0=0,c1=0,c2=0,c3=0;
    for (int l = 0; l < LSEQ / NSPLIT; ++l) {
        float4 x = *(const float4*)(xp + (size_t)l * NDIM);
        float w1 = sw[l0 + l], w2 = sw[LSEQ + l0 + l];
        a0 = fmaf(x.x, w1, a0); a1 = fmaf(x.y, w1, a1);
        a2 = fmaf(x.z, w1, a2); a3 = fmaf(x.w, w1, a3);
        c0 = fmaf(x.x, w2, c0); c1 = fmaf(x.y, w2, c1);
        c2 = fmaf(x.z, w2, c2); c3 = fmaf(x.w, w2, c3);
        ushort4 u; u.x = f2bf(x.x); u.y = f2bf(x.y); u.z = f2bf(x.z); u.w = f2bf(x.w);
        *(ushort4*)(xbp + (size_t)l * NDIM) = u;
    }
    size_t po = ((size_t)sp * BATCH + b) * NDIM + tid * 4;
    *(float4*)(P1 + po) = make_float4(a0, a1, a2, a3);
    *(float4*)(P2 + po) = make_float4(c0, c1, c2, c3);
}

// ---------------------------------------------------------------------------
// Kernel 2: fused reduce + softmax-denominator stats (unchanged)
// ---------------------------------------------------------------------------
__global__ __launch_bounds__(256) void stats_kernel(
    const float* __restrict__ P1, const float* __restrict__ P2,
    float* __restrict__ s1, float* __restrict__ s2, float* __restrict__ rd)
{
    __shared__ float s1s[NDIM];
    __shared__ float s2s[128];
    int t = threadIdx.x;
    int b = blockIdx.x >> 3, sl = blockIdx.x & 7;
    int j0 = sl * 128;

    #pragma unroll
    for (int q = 0; q < 4; ++q) {
        int n = q * 256 + t;
        float a = 0.f;
        #pragma unroll
        for (int sp = 0; sp < NSPLIT; ++sp)
            a += P1[((size_t)sp * BATCH + b) * NDIM + n];
        s1s[n] = a;
        if (sl == 0) s1[b * NDIM + n] = a;
    }
    if (t < 128) {
        int j = j0 + t;
        float c = 0.f;
        #pragma unroll
        for (int sp = 0; sp < NSPLIT; ++sp)
            c += P2[((size_t)sp * BATCH + b) * NDIM + j];
        s2s[t] = c;
        s2[b * NDIM + j] = c;
    }
    __syncthreads();

    int jl = t >> 1, half = t & 1;
    int jg = j0 + jl;
    float s2j = s2s[jl];
    float sum = 0.f;
    int i0 = half * 512;
    for (int i = i0; i < i0 + 512; ++i) {
        float v = s1s[i] + s2j;
        v = fmaxf(v, 0.01f * v);          // leaky relu
        if (i == jg) v = 0.f;             // diag of e zeroed before softmax
        sum += __expf(v);
    }
    sum += __shfl_xor(sum, 1);
    if (half == 0) rd[b * NDIM + jg] = 1.0f / sum;
}

// ---------------------------------------------------------------------------
// Kernel 3: Bt[b][i][j] = exp(e_ij) * rd[b,j] in bf16 (unchanged)
// ---------------------------------------------------------------------------
__global__ __launch_bounds__(256) void btgen_kernel(
    const float* __restrict__ s1, const float* __restrict__ s2,
    const float* __restrict__ rd, unsigned short* __restrict__ Bt)
{
    int wid = threadIdx.x >> 6, lane = threadIdx.x & 63;
    int r = blockIdx.x * 4 + wid;          // (b,i) flat
    int b = r >> 10, i = r & 1023;
    float s1i = s1[r];
    const float* s2b = s2 + b * NDIM;
    const float* rdb = rd + b * NDIM;
    unsigned short* outp = Bt + (size_t)r * NDIM;

    #pragma unroll
    for (int q = 0; q < 2; ++q) {
        int j0 = q * 512 + lane * 8;
        float sv[8], rv[8];
        #pragma unroll
        for (int h = 0; h < 2; ++h) {
            float4 s4 = *(const float4*)(s2b + j0 + h * 4);
            float4 r4 = *(const float4*)(rdb + j0 + h * 4);
            sv[h*4+0]=s4.x; sv[h*4+1]=s4.y; sv[h*4+2]=s4.z; sv[h*4+3]=s4.w;
            rv[h*4+0]=r4.x; rv[h*4+1]=r4.y; rv[h*4+2]=r4.z; rv[h*4+3]=r4.w;
        }
        bf16x8 v;
        #pragma unroll
        for (int k = 0; k < 8; ++k) {
            float e = s1i + sv[k];
            e = fmaxf(e, 0.01f * e);       // leaky relu
            if (j0 + k == i) e = 0.f;      // diag of e zeroed (alpha nonzero there)
            v[k] = (short)f2bf(__expf(e) * rv[k]);
        }
        *(bf16x8*)&outp[j0] = v;
    }
}

// ---------------------------------------------------------------------------
// Kernel 4: batched GEMM  out[b] = sigmoid( Xb[b] (512x1024) @ Bt[b]^T )
//
// ROUND 4: geometry change, not schedule change. R1-R3 all hit ~50us because
// per-CU LDS-read volume (8 waves x 24KB/tile, A read 4x redundantly = 192
// ds_read_b128/tile = 2304cyc) matched the MFMA budget (2483cyc/tile) and
// barrier-lockstep serialized the two. NEW: 4 waves (2Mx2N), 1 wave/SIMD,
// per-wave 128x128 output (acc[8][8] = 256 VGPR, launch_bounds(256,1)).
//   - LDS redundancy A x2 + B x2: 128 reads/CU/tile (1536cyc) < MFMA
//     (2483cyc/tile) -> LDS no longer binding.
//   - 1 wave/SIMD: no matrix-pipe contention; compiler's fine-lgkm
//     interleave (R1-proven) overlaps own reads with own MFMAs.
//   - Staging machinery IDENTICAL to R1 (ring-4 bufs, pre-swizzled
//     global_load_lds, WAITVM-then-barrier discipline), rescaled to 256
//     threads: 8 chunks/thread/tile, lead 3 tiles = 24 out, entry vmcnt(16),
//     tail drain 16 -> 8 -> 0.
// ---------------------------------------------------------------------------
#define WAITVM(n) asm volatile("s_waitcnt vmcnt(" #n ")" ::: "memory")
#define FENCE()   asm volatile("" ::: "memory")

#define DO_STAGE(bufi) {                                                        \
    _Pragma("unroll")                                                           \
    for (int j = 0; j < 8; ++j) {                                               \
        __builtin_amdgcn_global_load_lds(                                       \
            (const __attribute__((address_space(1))) void*)srcp[j],             \
            (__attribute__((address_space(3))) void*)(LdsC + (bufi) * 32768 +   \
                                                      ldst0 + j * 4096),        \
            16, 0, 0);                                                          \
        srcp[j] += 64;  /* advance k by 32 bf16 per tile */                     \
    } }

#define COMPUTE(bufi) {                                                         \
    const char* Lb = LdsC + (bufi) * 32768;                                     \
    bf16x8 av[8], bv[8];                                                        \
    _Pragma("unroll")                                                           \
    for (int mi = 0; mi < 8; ++mi)                                              \
        av[mi] = *(const bf16x8*)(Lb + abase0 + mi * 2048);                     \
    _Pragma("unroll")                                                           \
    for (int ni = 0; ni < 8; ++ni)                                              \
        bv[ni] = *(const bf16x8*)(Lb + bbase0 + ni * 2048);                     \
    _Pragma("unroll")                                                           \
    for (int ni = 0; ni < 8; ++ni)                                              \
        _Pragma("unroll")                                                       \
        for (int mi = 0; mi < 8; ++mi)                                          \
            acc[mi][ni] = __builtin_amdgcn_mfma_f32_16x16x32_bf16(              \
                av[mi], bv[ni], acc[mi][ni], 0, 0, 0);                          \
}

__global__ __launch_bounds__(256, 1) void gemm_kernel(
    const unsigned short* __restrict__ Xb, const unsigned short* __restrict__ Bt,
    float* __restrict__ out)
{
    // 4 ring buffers x 32 KiB (256 composite rows x 128 B) = 128 KiB
    __shared__ __align__(16) unsigned short LDSU[65536];
    char* LdsC = (char*)LDSU;

    const int tid = threadIdx.x, lane = tid & 63, wid = tid >> 6;
    const int wm = wid >> 1, wn = wid & 1;      // 2 x 2 wave grid, 128x128/wave

    // block mapping: 8 blocks/batch all on one XCD (flat&7 == b&7),
    // 4 batches per XCD, grid 256 = exactly 1 block/CU.
    int flat  = blockIdx.x;
    int xcd   = flat & 7;
    int p     = flat >> 3;
    int b     = (p >> 3) * 8 + xcd;
    int inner = p & 7;
    int mt = inner & 1, nt = inner >> 1;
    int l0 = mt * 256, n0 = nt * 256;

    const char* XgB = (const char*)(Xb + ((size_t)b * LSEQ + l0) * NDIM);
    const char* BgB = (const char*)(Bt + ((size_t)b * NDIM + n0) * NDIM);

    // Staging (R1-identical swizzle): chunk c = tid + j*256 fills LDS bytes
    // [c*16, c*16+16). Composite row r = c>>3 (128 B: logical A 0..63 |
    // B 64..127), slot = c&7. Physical slot holds logical offset
    // (slot*16) ^ ((r&7)<<4)  [involution, applied on the GLOBAL source].
    const char* srcp[8];
    #pragma unroll
    for (int j = 0; j < 8; ++j) {
        int c = tid + j * 256;
        int r = c >> 3, slot = c & 7;
        int off = (slot * 16) ^ ((r & 7) << 4);
        srcp[j] = (off < 64) ? XgB + (size_t)r * 2048 + off
                             : BgB + (size_t)r * 2048 + (off - 64);
    }
    const int ldst0 = wid * 1024;   // wave-uniform LDS base (+j*4096+buf*32768)

    // Fragment read offsets (same involution on the read side; R1-verified
    // conflict-free: 16 lanes spread 8 bank-groups, 2-way residual = free).
    const int rsel = lane & 15, kq = lane >> 4;
    const int swz  = (rsel & 7) << 4;
    const int abase0 = wm * 16384 + rsel * 128 + ((kq * 16) ^ swz);
    const int bbase0 = wn * 16384 + rsel * 128 + ((64 + kq * 16) ^ swz);

    f32x4 acc[8][8] = {};

    // prologue: 3-tile lead (24 loads/thread outstanding)
    DO_STAGE(0); DO_STAGE(1); DO_STAGE(2);

    // main loop: tiles 0..28 stage t+3; vmcnt(16) leaves t+1,t+2 in flight.
    // WAITVM-then-barrier: all waves' tile-t loads complete before any read.
    // WAR: buffer (t+3)&3 == (t-1)&3; every wave's t-1 ds_reads were consumed
    // by its own MFMAs (lgkm-gated) before it reached this barrier.
    for (int t = 0; t < 29; ++t) {
        WAITVM(16);
        FENCE(); __builtin_amdgcn_s_barrier(); FENCE();
        DO_STAGE((t + 3) & 3);
        COMPUTE(t & 3);
    }
    // epilogue drain: tiles 29,30,31 (no more stages) 16 -> 8 -> 0
    WAITVM(16); FENCE(); __builtin_amdgcn_s_barrier(); FENCE(); COMPUTE(1);
    WAITVM(8);  FENCE(); __builtin_amdgcn_s_barrier(); FENCE(); COMPUTE(2);
    WAITVM(0);  FENCE(); __builtin_amdgcn_s_barrier(); FENCE(); COMPUTE(3);

    // epilogue: C/D layout col=lane&15, row=(lane>>4)*4+reg  [m89/m91 verified]
    float* outb = out + ((size_t)b * LSEQ + l0) * NDIM + n0;
    const int rq = lane >> 4, cl = lane & 15;
    #pragma unroll
    for (int mi = 0; mi < 8; ++mi)
        #pragma unroll
        for (int ni = 0; ni < 8; ++ni) {
            int col = wn * 128 + ni * 16 + cl;
            #pragma unroll
            for (int r2 = 0; r2 < 4; ++r2) {
                int row = wm * 128 + mi * 16 + rq * 4 + r2;
                float v = acc[mi][ni][r2];
                outb[(size_t)row * NDIM + col] = 1.0f / (1.0f + __expf(-v));
            }
        }
}

#undef WAITVM
#undef FENCE
#undef DO_STAGE
#undef COMPUTE

// ---------------------------------------------------------------------------
extern "C" void kernel_launch(void* const* d_in, const int* in_sizes, int n_in,
                              void* d_out, int out_size, void* d_ws, size_t ws_size,
                              hipStream_t stream) {
    (void)in_sizes; (void)n_in; (void)out_size; (void)ws_size;
    const float* X = (const float*)d_in[0];
    const float* W = (const float*)d_in[1];
    float* out = (float*)d_out;

    // workspace: s1|s2|rd (32K floats each) | P1|P2 (512K floats each)
    //            | Xb bf16 32MB | Bt bf16 64MB   (~100.4 MB, unchanged)
    float* s1 = (float*)d_ws;
    float* s2 = s1 + BATCH * NDIM;
    float* rd = s2 + BATCH * NDIM;
    float* P1 = rd + BATCH * NDIM;
    float* P2 = P1 + (size_t)NSPLIT * BATCH * NDIM;
    unsigned short* Xb = (unsigned short*)(P2 + (size_t)NSPLIT * BATCH * NDIM);
    unsigned short* Bt = Xb + (size_t)BATCH * LSEQ * NDIM;

    prep_kernel<<<dim3(NSPLIT, BATCH), 256, 0, stream>>>(X, W, Xb, P1, P2);
    stats_kernel<<<256, 256, 0, stream>>>(P1, P2, s1, s2, rd);
    btgen_kernel<<<(BATCH * NDIM) / 4, 256, 0, stream>>>(s1, s2, rd, Bt);
    gemm_kernel<<<256, 256, 0, stream>>>(Xb, Bt, out);
}

// Round 5
// 189.058 us; speedup vs baseline: 1.0299x; 1.0299x over previous
//
#include <hip/hip_runtime.h>
#include <hip/hip_bf16.h>

#define BATCH 32
#define LSEQ  512
#define NDIM  1024
#define NSPLIT 32

typedef __attribute__((ext_vector_type(8))) short bf16x8;
typedef __attribute__((ext_vector_type(4))) float f32x4;

__device__ __forceinline__ unsigned short f2bf(float x) {
    __hip_bfloat16 h = __float2bfloat16(x);
    return __builtin_bit_cast(unsigned short, h);
}

// ---------------------------------------------------------------------------
// Kernel 1: fused X fp32 -> bf16 conversion + s1/s2 partial sums.
// R5: NSPLIT 16->32 (1024 blocks = 16 waves/CU), float4 loads kept.
// ---------------------------------------------------------------------------
__global__ __launch_bounds__(256) void prep_kernel(
    const float* __restrict__ X, const float* __restrict__ W,
    unsigned short* __restrict__ Xb, float* __restrict__ P1, float* __restrict__ P2)
{
    __shared__ float sw[2 * LSEQ];
    int tid = threadIdx.x;
    for (int i = tid; i < 2 * LSEQ; i += 256) sw[i] = W[i];
    __syncthreads();

    int b  = blockIdx.y;
    int sp = blockIdx.x;
    int l0 = sp * (LSEQ / NSPLIT);
    size_t base = ((size_t)b * LSEQ + l0) * NDIM + tid * 4;
    const float* xp = X + base;
    unsigned short* xbp = Xb + base;

    float a0=0,a1=0,a2=0,a3=0, c0=0,c1=0,c2=0,c3=0;
    #pragma unroll
    for (int l = 0; l < LSEQ / NSPLIT; ++l) {
        float4 x = *(const float4*)(xp + (size_t)l * NDIM);
        float w1 = sw[l0 + l], w2 = sw[LSEQ + l0 + l];
        a0 = fmaf(x.x, w1, a0); a1 = fmaf(x.y, w1, a1);
        a2 = fmaf(x.z, w1, a2); a3 = fmaf(x.w, w1, a3);
        c0 = fmaf(x.x, w2, c0); c1 = fmaf(x.y, w2, c1);
        c2 = fmaf(x.z, w2, c2); c3 = fmaf(x.w, w2, c3);
        ushort4 u; u.x = f2bf(x.x); u.y = f2bf(x.y); u.z = f2bf(x.z); u.w = f2bf(x.w);
        *(ushort4*)(xbp + (size_t)l * NDIM) = u;
    }
    size_t po = ((size_t)sp * BATCH + b) * NDIM + tid * 4;
    *(float4*)(P1 + po) = make_float4(a0, a1, a2, a3);
    *(float4*)(P2 + po) = make_float4(c0, c1, c2, c3);
}

// ---------------------------------------------------------------------------
// Kernel 2: fused reduce + softmax-denominator stats.
// R5: emits lrd = -log(sum) instead of rd = 1/sum (gemm folds it into exp).
// ---------------------------------------------------------------------------
__global__ __launch_bounds__(256) void stats_kernel(
    const float* __restrict__ P1, const float* __restrict__ P2,
    float* __restrict__ s1, float* __restrict__ s2, float* __restrict__ lrd)
{
    __shared__ float s1s[NDIM];
    __shared__ float s2s[128];
    int t = threadIdx.x;
    int b = blockIdx.x >> 3, sl = blockIdx.x & 7;
    int j0 = sl * 128;

    #pragma unroll
    for (int q = 0; q < 4; ++q) {
        int n = q * 256 + t;
        float a = 0.f;
        #pragma unroll
        for (int sp = 0; sp < NSPLIT; ++sp)
            a += P1[((size_t)sp * BATCH + b) * NDIM + n];
        s1s[n] = a;
        if (sl == 0) s1[b * NDIM + n] = a;
    }
    if (t < 128) {
        int j = j0 + t;
        float c = 0.f;
        #pragma unroll
        for (int sp = 0; sp < NSPLIT; ++sp)
            c += P2[((size_t)sp * BATCH + b) * NDIM + j];
        s2s[t] = c;
        s2[b * NDIM + j] = c;
    }
    __syncthreads();

    int jl = t >> 1, half = t & 1;
    int jg = j0 + jl;
    float s2j = s2s[jl];
    float sum = 0.f;
    int i0 = half * 512;
    for (int i = i0; i < i0 + 512; ++i) {
        float v = s1s[i] + s2j;
        v = fmaxf(v, 0.01f * v);          // leaky relu
        if (i == jg) v = 0.f;             // diag of e zeroed before softmax
        sum += __expf(v);
    }
    sum += __shfl_xor(sum, 1);
    if (half == 0) lrd[b * NDIM + jg] = -__logf(sum);
}

// ---------------------------------------------------------------------------
// Kernel 3 (FUSED GEMM): out[b] = sigmoid( Xb[b] (512x1024) @ B^T ) where
//   B[i][j] = exp( lrelu(s1_i + s2_j)[diag->0] + lrd_j )  computed IN-KERNEL.
// btgen + the 64MB Bt HBM round-trip are eliminated.
//
// Geometry: R1 winner — 256x256 tile, 8 waves (2Mx4N), 512 thr, 2 waves/SIMD.
// BK=64 (128B rows). LDS: A[2][256][128B] @0 (64KB, global_load_lds lead-1,
// pre-swizzled source), B[2][256][128B] @65536 (64KB, ds_write-generated),
// s2s @131072 (4KB), lrds @135168 (4KB). Total 136 KiB.
// Swizzle both regions: phys_off = log_off ^ ((row&7)<<4) — same involution
// R1 measured at 0 bank conflicts (128B rows = 32-bank stride).
//
// Per iter t: STAGE A(t+1) (4 DMA) | MFMA ks=0 | BGEN B(t+1) (VALU/trans,
// overlaps other wave's MFMA) | MFMA ks=1 | lgkm0+vmcnt0+barrier (loads had
// ~2500cy to land -> drain is stall-free).
// ---------------------------------------------------------------------------
#define WAITVM0() asm volatile("s_waitcnt vmcnt(0)" ::: "memory")
#define LGKM0()   asm volatile("s_waitcnt lgkmcnt(0)" ::: "memory")
#define BARF()    do { asm volatile("" ::: "memory");                          \
                       __builtin_amdgcn_s_barrier();                           \
                       asm volatile("" ::: "memory"); } while (0)

#define STAGE(DB) {                                                            \
    _Pragma("unroll")                                                          \
    for (int j = 0; j < 4; ++j) {                                              \
        __builtin_amdgcn_global_load_lds(                                      \
            (const __attribute__((address_space(1))) void*)srcp[j],            \
            (__attribute__((address_space(3))) void*)(LdsC + (DB) * 32768 +    \
                tid * 16 + j * 8192), 16, 0, 0);                               \
        srcp[j] += 128;  /* next BK=64 slice */                                \
    } }

#define BGEN(T2, DB) {                                                         \
    const float* s2p = s2s + (T2) * 64 + jb * 8;                               \
    const float* ldp = lrds + (T2) * 64 + jb * 8;                              \
    float4 sa = *(const float4*)(s2p);                                         \
    float4 sb = *(const float4*)(s2p + 4);                                     \
    float4 la = *(const float4*)(ldp);                                         \
    float4 lb = *(const float4*)(ldp + 4);                                     \
    float sv[8] = {sa.x,sa.y,sa.z,sa.w,sb.x,sb.y,sb.z,sb.w};                   \
    float lv[8] = {la.x,la.y,la.z,la.w,lb.x,lb.y,lb.z,lb.w};                   \
    int jg0 = (T2) * 64 + jb * 8;                                              \
    _Pragma("unroll")                                                          \
    for (int q = 0; q < 4; ++q) {                                              \
        int rloc = wid * 32 + q * 8 + il;                                      \
        int ig = n0 + rloc;                                                    \
        bf16x8 w;                                                              \
        _Pragma("unroll")                                                      \
        for (int h = 0; h < 8; ++h) {                                          \
            float v = s1q[q] + sv[h];                                          \
            v = fmaxf(v, 0.01f * v);           /* leaky relu */                \
            if (jg0 + h == ig) v = 0.f;        /* diag of e zeroed */          \
            w[h] = (short)f2bf(__expf(v + lv[h]));                             \
        }                                                                      \
        *(bf16x8*)(LdsC + 65536 + (DB) * 32768 + rloc * 128 +                  \
                   ((jb * 16) ^ (il << 4))) = w;                               \
    } }

#define COMPUTE_KS(DB, KOF) {                                                  \
    bf16x8 av[8], bv[4];                                                       \
    _Pragma("unroll")                                                          \
    for (int mi = 0; mi < 8; ++mi)                                             \
        av[mi] = *(const bf16x8*)(LdsC + (DB) * 32768 + arow + mi * 2048 +     \
                                  (KOF));                                      \
    _Pragma("unroll")                                                          \
    for (int ni = 0; ni < 4; ++ni)                                             \
        bv[ni] = *(const bf16x8*)(LdsC + 65536 + (DB) * 32768 + brow +         \
                                  ni * 2048 + (KOF));                          \
    __builtin_amdgcn_s_setprio(1);                                             \
    _Pragma("unroll")                                                          \
    for (int ni = 0; ni < 4; ++ni)                                             \
        _Pragma("unroll")                                                      \
        for (int mi = 0; mi < 8; ++mi)                                         \
            acc[mi][ni] = __builtin_amdgcn_mfma_f32_16x16x32_bf16(             \
                av[mi], bv[ni], acc[mi][ni], 0, 0, 0);                         \
    __builtin_amdgcn_s_setprio(0);                                             \
}

__global__ __launch_bounds__(512, 2) void gemm_kernel(
    const unsigned short* __restrict__ Xb, const float* __restrict__ s1,
    const float* __restrict__ s2, const float* __restrict__ lrd,
    float* __restrict__ out)
{
    // A 2x32KB @0 | B 2x32KB @65536 | s2s 4KB @131072 | lrds 4KB @135168
    __shared__ __align__(16) char LdsC[139264];
    float* s2s  = (float*)(LdsC + 131072);
    float* lrds = (float*)(LdsC + 135168);

    const int tid = threadIdx.x, lane = tid & 63, wid = tid >> 6;
    const int wm = wid >> 2, wn = wid & 3;      // 2 x 4 wave grid, 128x64/wave

    // block mapping: 8 blocks/batch all on one XCD (flat&7 == b&7),
    // 4 batches per XCD, grid 256 = exactly 1 block/CU.
    int flat  = blockIdx.x;
    int xcd   = flat & 7;
    int p     = flat >> 3;
    int b     = (p >> 3) * 8 + xcd;
    int inner = p & 7;
    int mt = inner & 1, nt = inner >> 1;
    int l0 = mt * 256, n0 = nt * 256;

    const char* XgB = (const char*)(Xb + ((size_t)b * LSEQ + l0) * NDIM);

    // A staging sources (pre-swizzled involution, rule #21): chunk c=tid+j*512,
    // row r=c>>3 (256 rows x 8 chunks of 16B = 128B = BK 64 bf16), slot=c&7.
    const char* srcp[4];
    #pragma unroll
    for (int j = 0; j < 4; ++j) {
        int c = tid + j * 512;
        int r = c >> 3, slot = c & 7;
        srcp[j] = XgB + (size_t)r * 2048 + ((slot * 16) ^ ((r & 7) << 4));
    }

    // Fragment read bases (swz per-lane constant: row&7 == rsel&7).
    const int rsel = lane & 15, kq = lane >> 4;
    const int swz  = (rsel & 7) << 4;
    const int kof0 = (kq * 16) ^ swz;
    const int kof1 = (64 + kq * 16) ^ swz;
    const int arow = (wm * 128 + rsel) * 128;
    const int brow = (wn * 64 + rsel) * 128;

    // B-gen lane roles: jb = k-chunk (8 j each), il = row-within-8.
    const int jb = lane & 7, il = lane >> 3;

    // preload s2/lrd panels for this batch into LDS (8KB)
    {
        const float* s2g = s2 + (size_t)b * NDIM;
        const float* ldg = lrd + (size_t)b * NDIM;
        if (tid < 256) *(float4*)(s2s + tid * 4) = *(const float4*)(s2g + tid * 4);
        else *(float4*)(lrds + (tid - 256) * 4) = *(const float4*)(ldg + (tid - 256) * 4);
    }
    STAGE(0);                 // A tile 0 -> A[0]
    __syncthreads();          // s2s/lrds visible (also drains the 4 DMAs)

    float s1q[4];
    #pragma unroll
    for (int q = 0; q < 4; ++q)
        s1q[q] = s1[(size_t)b * NDIM + n0 + wid * 32 + q * 8 + il];

    f32x4 acc[8][4] = {};

    BGEN(0, 0);               // B tile 0 -> B[0]
    LGKM0(); BARF();

    // main loop: 16 K-tiles, double-buffered lead-1
    for (int t = 0; t < 15; ++t) {
        int db = t & 1, dn = db ^ 1;
        STAGE(dn);            // A(t+1); loads get the whole tile to land
        COMPUTE_KS(db, kof0);
        BGEN(t + 1, dn);      // B(t+1): VALU/trans overlaps other wave's MFMA
        COMPUTE_KS(db, kof1);
        LGKM0(); WAITVM0(); BARF();
    }
    COMPUTE_KS(1, kof0);      // t = 15
    COMPUTE_KS(1, kof1);

    // epilogue: C/D layout col=lane&15, row=(lane>>4)*4+reg  [m89/m91 verified]
    float* outb = out + ((size_t)b * LSEQ + l0) * NDIM + n0;
    const int rq = lane >> 4, cl = lane & 15;
    #pragma unroll
    for (int mi = 0; mi < 8; ++mi)
        #pragma unroll
        for (int ni = 0; ni < 4; ++ni) {
            int col = wn * 64 + ni * 16 + cl;
            #pragma unroll
            for (int r2 = 0; r2 < 4; ++r2) {
                int row = wm * 128 + mi * 16 + rq * 4 + r2;
                float v = acc[mi][ni][r2];
                outb[(size_t)row * NDIM + col] = 1.0f / (1.0f + __expf(-v));
            }
        }
}

#undef WAITVM0
#undef LGKM0
#undef BARF
#undef STAGE
#undef BGEN
#undef COMPUTE_KS

// ---------------------------------------------------------------------------
extern "C" void kernel_launch(void* const* d_in, const int* in_sizes, int n_in,
                              void* d_out, int out_size, void* d_ws, size_t ws_size,
                              hipStream_t stream) {
    (void)in_sizes; (void)n_in; (void)out_size; (void)ws_size;
    const float* X = (const float*)d_in[0];
    const float* W = (const float*)d_in[1];
    float* out = (float*)d_out;

    // workspace: s1|s2|lrd (32K floats each) | P1|P2 (1M floats each)
    //            | Xb bf16 32MB   (~40.4 MB; Bt eliminated)
    float* s1 = (float*)d_ws;
    float* s2 = s1 + BATCH * NDIM;
    float* lrd = s2 + BATCH * NDIM;
    float* P1 = lrd + BATCH * NDIM;
    float* P2 = P1 + (size_t)NSPLIT * BATCH * NDIM;
    unsigned short* Xb = (unsigned short*)(P2 + (size_t)NSPLIT * BATCH * NDIM);

    prep_kernel<<<dim3(NSPLIT, BATCH), 256, 0, stream>>>(X, W, Xb, P1, P2);
    stats_kernel<<<256, 256, 0, stream>>>(P1, P2, s1, s2, lrd);
    gemm_kernel<<<256, 512, 0, stream>>>(Xb, s1, s2, lrd, out);
}

// Round 6
// 173.464 us; speedup vs baseline: 1.1225x; 1.0899x over previous
//
#include <hip/hip_runtime.h>
#include <hip/hip_bf16.h>

#define BATCH 32
#define LSEQ  512
#define NDIM  1024
#define NSPLIT 16

typedef __attribute__((ext_vector_type(8))) short bf16x8;
typedef __attribute__((ext_vector_type(4))) float f32x4;

__device__ __forceinline__ unsigned short f2bf(float x) {
    __hip_bfloat16 h = __float2bfloat16(x);
    return __builtin_bit_cast(unsigned short, h);
}

// ---------------------------------------------------------------------------
// Kernel 1: fused X fp32 -> bf16 conversion + s1/s2 partial sums
// (R1 form, NSPLIT=16; R5's 32-split regressed)
// ---------------------------------------------------------------------------
__global__ __launch_bounds__(256) void prep_kernel(
    const float* __restrict__ X, const float* __restrict__ W,
    unsigned short* __restrict__ Xb, float* __restrict__ P1, float* __restrict__ P2)
{
    __shared__ float sw[2 * LSEQ];
    int tid = threadIdx.x;
    for (int i = tid; i < 2 * LSEQ; i += 256) sw[i] = W[i];
    __syncthreads();

    int b  = blockIdx.y;
    int sp = blockIdx.x;
    int l0 = sp * (LSEQ / NSPLIT);
    size_t base = ((size_t)b * LSEQ + l0) * NDIM + tid * 4;
    const float* xp = X + base;
    unsigned short* xbp = Xb + base;

    float a0=0,a1=0,a2=0,a3=0, c0=0,c1=0,c2=0,c3=0;
    for (int l = 0; l < LSEQ / NSPLIT; ++l) {
        float4 x = *(const float4*)(xp + (size_t)l * NDIM);
        float w1 = sw[l0 + l], w2 = sw[LSEQ + l0 + l];
        a0 = fmaf(x.x, w1, a0); a1 = fmaf(x.y, w1, a1);
        a2 = fmaf(x.z, w1, a2); a3 = fmaf(x.w, w1, a3);
        c0 = fmaf(x.x, w2, c0); c1 = fmaf(x.y, w2, c1);
        c2 = fmaf(x.z, w2, c2); c3 = fmaf(x.w, w2, c3);
        ushort4 u; u.x = f2bf(x.x); u.y = f2bf(x.y); u.z = f2bf(x.z); u.w = f2bf(x.w);
        *(ushort4*)(xbp + (size_t)l * NDIM) = u;
    }
    size_t po = ((size_t)sp * BATCH + b) * NDIM + tid * 4;
    *(float4*)(P1 + po) = make_float4(a0, a1, a2, a3);
    *(float4*)(P2 + po) = make_float4(c0, c1, c2, c3);
}

// ---------------------------------------------------------------------------
// Kernel 2: fused reduce + softmax-denominator stats; emits lrd = -log(sum)
// ---------------------------------------------------------------------------
__global__ __launch_bounds__(256) void stats_kernel(
    const float* __restrict__ P1, const float* __restrict__ P2,
    float* __restrict__ s1, float* __restrict__ s2, float* __restrict__ lrd)
{
    __shared__ float s1s[NDIM];
    __shared__ float s2s[128];
    int t = threadIdx.x;
    int b = blockIdx.x >> 3, sl = blockIdx.x & 7;
    int j0 = sl * 128;

    #pragma unroll
    for (int q = 0; q < 4; ++q) {
        int n = q * 256 + t;
        float a = 0.f;
        #pragma unroll
        for (int sp = 0; sp < NSPLIT; ++sp)
            a += P1[((size_t)sp * BATCH + b) * NDIM + n];
        s1s[n] = a;
        if (sl == 0) s1[b * NDIM + n] = a;
    }
    if (t < 128) {
        int j = j0 + t;
        float c = 0.f;
        #pragma unroll
        for (int sp = 0; sp < NSPLIT; ++sp)
            c += P2[((size_t)sp * BATCH + b) * NDIM + j];
        s2s[t] = c;
        s2[b * NDIM + j] = c;
    }
    __syncthreads();

    int jl = t >> 1, half = t & 1;
    int jg = j0 + jl;
    float s2j = s2s[jl];
    float sum = 0.f;
    int i0 = half * 512;
    for (int i = i0; i < i0 + 512; ++i) {
        float v = s1s[i] + s2j;
        v = fmaxf(v, 0.01f * v);          // leaky relu
        if (i == jg) v = 0.f;             // diag of e zeroed before softmax
        sum += __expf(v);
    }
    sum += __shfl_xor(sum, 1);
    if (half == 0) lrd[b * NDIM + jg] = -__logf(sum);
}

// ---------------------------------------------------------------------------
// Kernel 3 (FUSED GEMM): out[b] = sigmoid( Xb[b] @ B^T ),
//   B[i][j] = exp( lrelu(s1_i + s2_j)[diag->0] + lrd_j ) generated in-LDS.
//
// ROUND 6: cross-block overlap. R1-R5 cycle budget: MFMA 39.7k cyc/CU and
// LDS-read 37k cyc/CU are co-equal CU-shared pipes; barrier lockstep
// SERIALIZES them -> the invariant ~50us. Fix = 2 independent blocks/CU
// (m97's mechanism): block A's LDS/VALU phases run under block B's MFMA.
//   tile 256M x 128N, 4 waves (2Mx2N, per-wave 128x64, acc[8][4]), BK=32.
//   LDS/block 56KB: A dbuf 2x16KB @0 | B dbuf 2x8KB @32768 | s2s @49152 |
//   lrds @53248.  grid 512 = 2 blocks/CU, launch_bounds(256,2).
//   64B logical rows stored as 128B SUPERROWS (row pair) with involution
//   phys_inner = log_inner ^ ((sr&7)<<4): fragment reads, BGEN writes and
//   staging are all 2-way per 16-lane group = conflict-free (verified vs
//   R1's measured-0 pattern; element (r=5,k=32) round-trip checked).
//   One barrier per tile; A staged lead-1 (4 global_load_lds, pre-swizzled
//   source); BGEN(t+1) overlaps COMPUTE(t) and the other block entirely.
// ---------------------------------------------------------------------------
#define WAITVM0() asm volatile("s_waitcnt vmcnt(0)" ::: "memory")
#define LGKM0()   asm volatile("s_waitcnt lgkmcnt(0)" ::: "memory")
#define BARF()    do { asm volatile("" ::: "memory");                          \
                       __builtin_amdgcn_s_barrier();                           \
                       asm volatile("" ::: "memory"); } while (0)

#define STAGE(DN) {                                                            \
    _Pragma("unroll")                                                          \
    for (int j = 0; j < 4; ++j) {                                              \
        __builtin_amdgcn_global_load_lds(                                      \
            (const __attribute__((address_space(1))) void*)srcp[j],            \
            (__attribute__((address_space(3))) void*)(LdsC + (DN) * 16384 +    \
                tid * 16 + j * 4096), 16, 0, 0);                               \
        srcp[j] += 64;  /* advance k by 32 bf16 */                             \
    } }

#define BGEN(TT, DN) {                                                         \
    int k0f = (TT) * 32;                                                       \
    const float* s2p = s2s + k0f + jb8;                                        \
    const float* ldp = lrds + k0f + jb8;                                       \
    float4 sa = *(const float4*)(s2p);                                         \
    float4 sb = *(const float4*)(s2p + 4);                                     \
    float4 la = *(const float4*)(ldp);                                         \
    float4 lb = *(const float4*)(ldp + 4);                                     \
    float sv[8] = {sa.x,sa.y,sa.z,sa.w,sb.x,sb.y,sb.z,sb.w};                   \
    float lv[8] = {la.x,la.y,la.z,la.w,lb.x,lb.y,lb.z,lb.w};                   \
    _Pragma("unroll")                                                          \
    for (int q2 = 0; q2 < 2; ++q2) {                                           \
        int ig = n0 + rloc0 + q2 * 64;                                         \
        float s1i = s1v[q2];                                                   \
        bf16x8 w;                                                              \
        _Pragma("unroll")                                                      \
        for (int h = 0; h < 8; ++h) {                                          \
            float v = s1i + sv[h];                                             \
            v = fmaxf(v, 0.01f * v);           /* leaky relu */                \
            if (k0f + jb8 + h == ig) v = 0.f;  /* diag of e zeroed */          \
            w[h] = (short)f2bf(__expf(v + lv[h]));                             \
        }                                                                      \
        *(bf16x8*)(LdsC + 32768 + (DN) * 8192 + srbase + q2 * 4096 + bgin) = w;\
    } }

#define COMPUTE(DD) {                                                          \
    const char* La = LdsC + (DD) * 16384;                                      \
    const char* Lb = LdsC + 32768 + (DD) * 8192;                               \
    bf16x8 av[8], bv[4];                                                       \
    _Pragma("unroll")                                                          \
    for (int mi = 0; mi < 8; ++mi)                                             \
        av[mi] = *(const bf16x8*)(La + abase0 + mi * 1024);                    \
    _Pragma("unroll")                                                          \
    for (int ni = 0; ni < 4; ++ni)                                             \
        bv[ni] = *(const bf16x8*)(Lb + bbase0 + ni * 1024);                    \
    __builtin_amdgcn_s_setprio(1);                                             \
    _Pragma("unroll")                                                          \
    for (int ni = 0; ni < 4; ++ni)                                             \
        _Pragma("unroll")                                                      \
        for (int mi = 0; mi < 8; ++mi)                                         \
            acc[mi][ni] = __builtin_amdgcn_mfma_f32_16x16x32_bf16(             \
                av[mi], bv[ni], acc[mi][ni], 0, 0, 0);                         \
    __builtin_amdgcn_s_setprio(0);                                             \
}

__global__ __launch_bounds__(256, 2) void gemm_kernel(
    const unsigned short* __restrict__ Xb, const float* __restrict__ s1,
    const float* __restrict__ s2, const float* __restrict__ lrd,
    float* __restrict__ out)
{
    __shared__ __align__(16) char LdsC[57344];
    float* s2s  = (float*)(LdsC + 49152);
    float* lrds = (float*)(LdsC + 53248);

    const int tid = threadIdx.x, lane = tid & 63, wid = tid >> 6;
    const int wm = wid >> 1, wn = wid & 1;      // 2x2 wave grid, 128x64/wave

    // 512 blocks: xcd = flat&7; 4 batches/XCD; 16 blocks/batch (2mt x 8nt).
    int flat  = blockIdx.x;
    int xcd   = flat & 7;
    int p     = flat >> 3;
    int b     = (p >> 4) * 8 + xcd;
    int inner = p & 15;
    int mt = inner & 1, nt = inner >> 1;
    int l0 = mt * 256, n0 = nt * 128;

    const char* XgB = (const char*)(Xb + ((size_t)b * LSEQ + l0) * NDIM);

    // A staging sources (pre-swizzled, rule #21). Chunk c = tid + j*256 fills
    // LDS byte [c*16, c*16+16): superrow sr=c>>3, slot=c&7;
    // log_inner = (slot*16)^((sr&7)<<4); logical row r = 2*sr + (inner>=64).
    const char* srcp[4];
    #pragma unroll
    for (int j = 0; j < 4; ++j) {
        int c = tid + j * 256;
        int sr = c >> 3, slot = c & 7;
        int li = (slot * 16) ^ ((sr & 7) << 4);
        int r = sr * 2 + (li >> 6);
        srcp[j] = XgB + (size_t)r * 2048 + (li & 63);
    }

    // Fragment read bases: row r -> sr=r>>1; inner=((r&1)*64+kq*16)^((sr&7)<<4)
    // sr&7 reduces to (rsel>>1)&7 for all mi/ni/wm/wn -> per-lane constant.
    const int rsel = lane & 15, kq = lane >> 4;
    const int finner = (((rsel & 1) * 64) + kq * 16) ^ (((rsel >> 1) & 7) << 4);
    const int abase0 = (wm * 64 + (rsel >> 1)) * 128 + finner;
    const int bbase0 = (wn * 32 + (rsel >> 1)) * 128 + finner;

    // BGEN lane roles: rows rloc0(+64), k-slot jb = lane>>4 (8 floats each).
    const int rloc0 = wid * 16 + (lane & 15);
    const int jb8   = (lane >> 4) * 8;
    const int srbase = (rloc0 >> 1) * 128;
    const int bgin  = (((rloc0 & 1) * 64) + (lane >> 4) * 16)
                      ^ (((rloc0 >> 1) & 7) << 4);

    // panels: s2/lrd for batch b -> LDS (4KB each)
    {
        const float* s2g = s2 + (size_t)b * NDIM;
        const float* ldg = lrd + (size_t)b * NDIM;
        *(float4*)(s2s + tid * 4)  = *(const float4*)(s2g + tid * 4);
        *(float4*)(lrds + tid * 4) = *(const float4*)(ldg + tid * 4);
    }
    STAGE(0);                     // A tile 0
    __syncthreads();              // panels + A[0] visible (full drain)

    float s1v[2];
    s1v[0] = s1[(size_t)b * NDIM + n0 + rloc0];
    s1v[1] = s1[(size_t)b * NDIM + n0 + rloc0 + 64];

    f32x4 acc[8][4] = {};

    BGEN(0, 0);                   // B tile 0
    LGKM0(); BARF();

    // 32 K-tiles, lead-1 double buffer, ONE barrier per tile.
    // WAR: BGEN(t+1,dn) overwrites B[dn] last read in iter t-1, whose reads
    // completed before that iter's lgkm0+barrier; A[dn] DMA same argument.
    for (int t = 0; t < 31; ++t) {
        int d = t & 1, dn = d ^ 1;
        STAGE(dn);                // A(t+1) in flight across BGEN+COMPUTE
        BGEN(t + 1, dn);          // B(t+1): VALU, overlaps MFMA cross-wave/block
        COMPUTE(d);
        LGKM0(); WAITVM0(); BARF();
    }
    COMPUTE(1);                   // t = 31

    // epilogue: C/D layout col=lane&15, row=(lane>>4)*4+reg  [m89/m91 verified]
    float* outb = out + ((size_t)b * LSEQ + l0) * NDIM + n0;
    const int rq = lane >> 4, cl = lane & 15;
    #pragma unroll
    for (int mi = 0; mi < 8; ++mi)
        #pragma unroll
        for (int ni = 0; ni < 4; ++ni) {
            int col = wn * 64 + ni * 16 + cl;
            #pragma unroll
            for (int r2 = 0; r2 < 4; ++r2) {
                int row = wm * 128 + mi * 16 + rq * 4 + r2;
                float v = acc[mi][ni][r2];
                outb[(size_t)row * NDIM + col] = 1.0f / (1.0f + __expf(-v));
            }
        }
}

#undef WAITVM0
#undef LGKM0
#undef BARF
#undef STAGE
#undef BGEN
#undef COMPUTE

// ---------------------------------------------------------------------------
extern "C" void kernel_launch(void* const* d_in, const int* in_sizes, int n_in,
                              void* d_out, int out_size, void* d_ws, size_t ws_size,
                              hipStream_t stream) {
    (void)in_sizes; (void)n_in; (void)out_size; (void)ws_size;
    const float* X = (const float*)d_in[0];
    const float* W = (const float*)d_in[1];
    float* out = (float*)d_out;

    // workspace: s1|s2|lrd (32K floats) | P1|P2 (512K floats) | Xb bf16 32MB
    float* s1 = (float*)d_ws;
    float* s2 = s1 + BATCH * NDIM;
    float* lrd = s2 + BATCH * NDIM;
    float* P1 = lrd + BATCH * NDIM;
    float* P2 = P1 + (size_t)NSPLIT * BATCH * NDIM;
    unsigned short* Xb = (unsigned short*)(P2 + (size_t)NSPLIT * BATCH * NDIM);

    prep_kernel<<<dim3(NSPLIT, BATCH), 256, 0, stream>>>(X, W, Xb, P1, P2);
    stats_kernel<<<256, 256, 0, stream>>>(P1, P2, s1, s2, lrd);
    gemm_kernel<<<512, 256, 0, stream>>>(Xb, s1, s2, lrd, out);
}